// Round 15
// baseline (929.866 us; speedup 1.0000x reference)
//
#include <hip/hip_runtime.h>

// 6-layer pre-LN encoder, B=8 S=1024 D=512 H=8 DH=64 FFN=2048.
// Round 15: W1 back to gemm128 (R13 config; 64x128 regressed). NEW: LN folded
// into consuming GEMMs algebraically: LN(x)@W = inv*(x@(g*W)) - inv*mu*C1 + C2.
// g (and qscale) folded into prepped weights; C1/C2 precomputed per layer;
// ln_k replaced by tiny per-row stat_k (mu, inv). Removes the 8MB LN
// materialization per LN and one bf16 rounding.

#define SEQ 1024
#define ROWS 8192
#define QKVW 1536

using bf16x8 = __attribute__((ext_vector_type(8))) short;
using f32x4  = __attribute__((ext_vector_type(4))) float;

__device__ __forceinline__ unsigned short f2bf(float f) {
  union { float f; unsigned u; } v; v.f = f;
  unsigned r = v.u + 0x7FFFu + ((v.u >> 16) & 1u);   // RNE
  return (unsigned short)(r >> 16);
}
__device__ __forceinline__ float bf2f(unsigned short b) {
  union { unsigned u; float f; } v; v.u = ((unsigned)b) << 16;
  return v.f;
}

__device__ __forceinline__ float exp2_fast(float x) {
  float r;
  asm("v_exp_f32 %0, %1" : "=v"(r) : "v"(x));
  return r;
}

__device__ __forceinline__ unsigned cvtpk_bf16(float a, float b) {
  unsigned r;   // low16 = bf16(a), high16 = bf16(b)
  asm("v_cvt_pk_bf16_f32 %0, %1, %2" : "=v"(r) : "v"(a), "v"(b));
  return r;
}

__device__ __forceinline__ void gl16(const void* g, void* l) {
  typedef const unsigned int __attribute__((address_space(1)))* GP;
  typedef unsigned int __attribute__((address_space(3)))* LP;
  __builtin_amdgcn_global_load_lds((GP)g, (LP)l, 16, 0, 0);
}

// ---------------------------------------------------------------- weight prep
// plain transpose+cast (W2)
__global__ __launch_bounds__(256) void transpose_cast_k(
    const float* __restrict__ W, unsigned short* __restrict__ Wt,
    int K, int N, int lstride, float scale)
{
  __shared__ float tile[32][33];
  const int l = blockIdx.z;
  const float* Wl = W + (size_t)l * K * N;
  unsigned short* Wtl = Wt + (size_t)l * lstride;
  const int k0 = blockIdx.y * 32, n0 = blockIdx.x * 32;
  const int tx = threadIdx.x & 31, ty = threadIdx.x >> 5;
  #pragma unroll
  for (int i = ty; i < 32; i += 8)
    tile[i][tx] = Wl[(size_t)(k0 + i) * N + n0 + tx];
  __syncthreads();
  #pragma unroll
  for (int i = ty; i < 32; i += 8)
    Wtl[(size_t)(n0 + i) * K + k0 + tx] = f2bf(tile[tx][i] * scale);
}

// QKVO combined: z = l*4 + {0:Q,1:K,2:V,3:O}; Q/K/V fold g_attn (Q also qscale).
__global__ __launch_bounds__(256) void wprep4_k(
    const float* __restrict__ Wq, const float* __restrict__ Wk,
    const float* __restrict__ Wv, const float* __restrict__ Wo,
    const float* __restrict__ ga,
    unsigned short* __restrict__ WtQKV, unsigned short* __restrict__ WtO,
    float qscale)
{
  __shared__ float tile[32][33];
  const int z = blockIdx.z, l = z >> 2, which = z & 3;
  const float* W;
  unsigned short* Wtl;
  float scale = 1.0f;
  switch (which) {
    case 0: W = Wq; Wtl = WtQKV + (size_t)l * QKVW * 512;          scale = qscale; break;
    case 1: W = Wk; Wtl = WtQKV + (size_t)l * QKVW * 512 + 262144; break;
    case 2: W = Wv; Wtl = WtQKV + (size_t)l * QKVW * 512 + 524288; break;
    default: W = Wo; Wtl = WtO + (size_t)l * 262144;               break;
  }
  const float* Wl = W + (size_t)l * 512 * 512;
  const int k0 = blockIdx.y * 32, n0 = blockIdx.x * 32;
  const int tx = threadIdx.x & 31, ty = threadIdx.x >> 5;
  #pragma unroll
  for (int i = ty; i < 32; i += 8)
    tile[i][tx] = Wl[(size_t)(k0 + i) * 512 + n0 + tx];
  __syncthreads();
  const float gv = (which < 3) ? ga[l * 512 + k0 + tx] * scale : 1.0f;
  #pragma unroll
  for (int i = ty; i < 32; i += 8)
    Wtl[(size_t)(n0 + i) * 512 + k0 + tx] = f2bf(tile[tx][i] * gv);
}

// W1 with g_ffn fold
__global__ __launch_bounds__(256) void wprep1_k(
    const float* __restrict__ W, const float* __restrict__ gf,
    unsigned short* __restrict__ Wt)
{
  __shared__ float tile[32][33];
  const int l = blockIdx.z;
  const float* Wl = W + (size_t)l * 512 * 2048;
  unsigned short* Wtl = Wt + (size_t)l * 1048576;
  const int k0 = blockIdx.y * 32, n0 = blockIdx.x * 32;
  const int tx = threadIdx.x & 31, ty = threadIdx.x >> 5;
  #pragma unroll
  for (int i = ty; i < 32; i += 8)
    tile[i][tx] = Wl[(size_t)(k0 + i) * 2048 + n0 + tx];
  __syncthreads();
  const float gv = gf[l * 512 + k0 + tx];
  #pragma unroll
  for (int i = ty; i < 32; i += 8)
    Wtl[(size_t)(n0 + i) * 512 + k0 + tx] = f2bf(tile[tx][i] * gv);
}

// C1[n]=scale*sum_k g_k W[k][n]; C2[n]=scale*sum_k be_k W[k][n] (+bias[n])
__global__ __launch_bounds__(256) void cvec_k(
    const float* __restrict__ W, const float* __restrict__ g,
    const float* __restrict__ be, const float* __restrict__ bias, float scale,
    float* __restrict__ C1, float* __restrict__ C2, int N, int Cstride)
{
  const int l = blockIdx.y;
  const float* Wl = W + (size_t)l * 512 * N;
  const int t = threadIdx.x;
  const int n = blockIdx.x * 64 + (t & 63);
  const int sl = t >> 6;
  float s1 = 0.0f, s2 = 0.0f;
  for (int k = sl * 128; k < sl * 128 + 128; k++) {
    const float w = Wl[(size_t)k * N + n];
    s1 += g[l * 512 + k] * w;
    s2 += be[l * 512 + k] * w;
  }
  __shared__ float r1[256], r2[256];
  r1[t] = s1; r2[t] = s2;
  __syncthreads();
  if (sl == 0) {
    s1 = r1[t] + r1[t + 64] + r1[t + 128] + r1[t + 192];
    s2 = r2[t] + r2[t + 64] + r2[t + 128] + r2[t + 192];
    C1[(size_t)l * Cstride + n] = s1 * scale;
    C2[(size_t)l * Cstride + n] = s2 * scale + (bias ? bias[(size_t)l * N + n] : 0.0f);
  }
}

// ---------------------------------------------------------------- f32 -> bf16 convert (x, once)
__global__ __launch_bounds__(256) void cvt_k(
    const float* __restrict__ x, unsigned short* __restrict__ y, int n8)
{
  const int i = blockIdx.x * 256 + threadIdx.x;
  if (i >= n8) return;
  const float4 a = reinterpret_cast<const float4*>(x)[i * 2];
  const float4 b = reinterpret_cast<const float4*>(x)[i * 2 + 1];
  uint4 o;
  o.x = (unsigned)f2bf(a.x) | ((unsigned)f2bf(a.y) << 16);
  o.y = (unsigned)f2bf(a.z) | ((unsigned)f2bf(a.w) << 16);
  o.z = (unsigned)f2bf(b.x) | ((unsigned)f2bf(b.y) << 16);
  o.w = (unsigned)f2bf(b.z) | ((unsigned)f2bf(b.w) << 16);
  reinterpret_cast<uint4*>(y)[i] = o;
}

// ---------------------------------------------------------------- row stats (mu, inv) for LN fold
__global__ __launch_bounds__(256) void stat_k(
    const unsigned short* __restrict__ x, float2* __restrict__ mui, int rows)
{
  const int wid = (blockIdx.x << 2) | (threadIdx.x >> 6);
  const int lane = threadIdx.x & 63;
  if (wid >= rows) return;
  const uint4 u = reinterpret_cast<const uint4*>(x + (size_t)wid * 512)[lane];
  float f[8];
  f[0] = bf2f((unsigned short)(u.x & 0xffffu)); f[1] = bf2f((unsigned short)(u.x >> 16));
  f[2] = bf2f((unsigned short)(u.y & 0xffffu)); f[3] = bf2f((unsigned short)(u.y >> 16));
  f[4] = bf2f((unsigned short)(u.z & 0xffffu)); f[5] = bf2f((unsigned short)(u.z >> 16));
  f[6] = bf2f((unsigned short)(u.w & 0xffffu)); f[7] = bf2f((unsigned short)(u.w >> 16));
  float s = 0.0f, q = 0.0f;
  #pragma unroll
  for (int j = 0; j < 8; j++) { s += f[j]; q += f[j] * f[j]; }
  #pragma unroll
  for (int m = 32; m >= 1; m >>= 1) { s += __shfl_xor(s, m); q += __shfl_xor(q, m); }
  if (lane == 0) {
    const float mu = s * (1.0f / 512.0f);
    const float inv = rsqrtf(q * (1.0f / 512.0f) - mu * mu + 1e-3f);
    mui[wid] = make_float2(mu, inv);
  }
}

// ---------------------------------------------------------------- GEMM 128x128, BK=32, dbuf 2-phase
// QKV=true: blocks with n0>=1024 (V third) write transposed into vt.
// LNF=true: epilogue applies v = inv*(acc - mu*C1[col]) + C2[col].
template<bool RELU, bool HASBIAS, bool HASRES, bool OUTBF, bool QKV, bool LNF>
__global__ __launch_bounds__(256) void gemm128_k(
    const unsigned short* __restrict__ A,
    const unsigned short* __restrict__ Wt,
    const float* __restrict__ bias,
    const float* __restrict__ res,
    const float2* __restrict__ MUI,
    const float* __restrict__ C1,
    const float* __restrict__ C2,
    void* __restrict__ outp, unsigned short* __restrict__ vt,
    int M, int N, int K)
{
  __shared__ __align__(16) unsigned short As0[4096], Bs0[4096];
  __shared__ __align__(16) unsigned short As1[4096], Bs1[4096];
  const int t = threadIdx.x;
  const int nwg = gridDim.x * gridDim.y;
  const int bid = blockIdx.y * gridDim.x + blockIdx.x;
  const int nid = (bid & 7) * (nwg >> 3) + (bid >> 3);
  const int bx = nid % gridDim.x, by = nid / gridDim.x;
  const int m0 = by * 128, n0 = bx * 128;
  const int w = t >> 6, lane = t & 63, llo = lane & 15, lhi = lane >> 4;
  const int wr = w >> 1, wc = w & 1;

  const int sr = t >> 2, sg = (t & 3) ^ ((t >> 3) & 3);
  const unsigned short* pa = &A[(size_t)(m0 + sr) * K + sg * 8];
  const unsigned short* pb = &Wt[(size_t)(n0 + sr) * K + sg * 8];

#define GSTAGE128(AsX, BsX, koff) do { \
    gl16(pa + (koff), &AsX[t * 8]); \
    gl16(pa + (size_t)64 * K + (koff), &AsX[2048 + t * 8]); \
    gl16(pb + (koff), &BsX[t * 8]); \
    gl16(pb + (size_t)64 * K + (koff), &BsX[2048 + t * 8]); \
  } while (0)

  const int pgo = (lhi ^ ((llo >> 1) & 3)) * 8;

#define GCOMP128(AsX, BsX) do { \
    bf16x8 af[4], bfr[4]; \
    _Pragma("unroll") \
    for (int f = 0; f < 4; f++) { \
      af[f]  = *reinterpret_cast<const bf16x8*>(&AsX[(wr * 64 + f * 16 + llo) * 32 + pgo]); \
      bfr[f] = *reinterpret_cast<const bf16x8*>(&BsX[(wc * 64 + f * 16 + llo) * 32 + pgo]); \
    } \
    _Pragma("unroll") \
    for (int fi = 0; fi < 4; fi++) \
      _Pragma("unroll") \
      for (int fj = 0; fj < 4; fj++) \
        acc[fi][fj] = __builtin_amdgcn_mfma_f32_16x16x32_bf16(af[fi], bfr[fj], acc[fi][fj], 0, 0, 0); \
  } while (0)

  f32x4 acc[4][4] = {};
  GSTAGE128(As0, Bs0, 0);
  for (int k0 = 0; k0 < K; k0 += 64) {
    __syncthreads();
    GSTAGE128(As1, Bs1, k0 + 32);
    GCOMP128(As0, Bs0);
    __syncthreads();
    if (k0 + 64 < K) GSTAGE128(As0, Bs0, k0 + 64);
    GCOMP128(As1, Bs1);
  }
#undef GSTAGE128
#undef GCOMP128

  const int row0 = m0 + wr * 64, col0 = n0 + wc * 64;

  float2 muiA[4][4];
  float c1v[4], c2v[4];
  if (LNF) {
    #pragma unroll
    for (int fi = 0; fi < 4; fi++)
      #pragma unroll
      for (int i = 0; i < 4; i++)
        muiA[fi][i] = MUI[row0 + fi * 16 + lhi * 4 + i];
    #pragma unroll
    for (int fj = 0; fj < 4; fj++) {
      c1v[fj] = C1[col0 + fj * 16 + llo];
      c2v[fj] = C2[col0 + fj * 16 + llo];
    }
  }

  if (QKV && n0 >= 1024) {
    // V-section: write transposed directly into VT[bh][dv][s].
    const int bb2 = by >> 3;              // batch (m0/1024)
    const int s0 = (by & 7) * 128;        // s base within batch
    const int bh = bb2 * 8 + ((bx - 8) << 1) + wc;
    #pragma unroll
    for (int fi = 0; fi < 4; fi++)
      #pragma unroll
      for (int fj = 0; fj < 4; fj++) {
        float vv[4];
        #pragma unroll
        for (int i = 0; i < 4; i++) {
          float v = acc[fi][fj][i];
          if (LNF) v = muiA[fi][i].y * (v - muiA[fi][i].x * c1v[fj]) + c2v[fj];
          vv[i] = v;
        }
        ushort4 o;
        o.x = f2bf(vv[0]); o.y = f2bf(vv[1]); o.z = f2bf(vv[2]); o.w = f2bf(vv[3]);
        const int dv = fj * 16 + llo;
        *reinterpret_cast<ushort4*>(
            &vt[((size_t)bh * 64 + dv) * SEQ + s0 + wr * 64 + fi * 16 + lhi * 4]) = o;
      }
    return;
  }

  #pragma unroll
  for (int fi = 0; fi < 4; fi++)
    #pragma unroll
    for (int fj = 0; fj < 4; fj++)
      #pragma unroll
      for (int i = 0; i < 4; i++) {
        const int row = row0 + fi * 16 + lhi * 4 + i;
        const int col = col0 + fj * 16 + llo;
        float v = acc[fi][fj][i];
        if (LNF)     v = muiA[fi][i].y * (v - muiA[fi][i].x * c1v[fj]) + c2v[fj];
        if (HASBIAS) v += bias[col];
        if (HASRES)  v += res[(size_t)row * N + col];
        if (RELU)    v = fmaxf(v, 0.0f);
        if (OUTBF) ((unsigned short*)outp)[(size_t)row * N + col] = f2bf(v);
        else       ((float*)outp)[(size_t)row * N + col] = v;
      }
}

// ---------------------------------------------------------------- GEMM 64x128, BK=32, dbuf 2-phase
// RESBF: residual tensor is bf16.
template<bool RELU, bool HASBIAS, bool HASRES, bool OUTBF, bool RESBF>
__global__ __launch_bounds__(256) void gemm64_k(
    const unsigned short* __restrict__ A,
    const unsigned short* __restrict__ Wt,
    const float* __restrict__ bias,
    const void* __restrict__ res,
    void* __restrict__ outp, int M, int N, int K)
{
  __shared__ __align__(16) unsigned short As0[2048], Bs0[4096];
  __shared__ __align__(16) unsigned short As1[2048], Bs1[4096];
  const int t = threadIdx.x;
  const int nwg = gridDim.x * gridDim.y;
  const int bid = blockIdx.y * gridDim.x + blockIdx.x;
  const int nid = (bid & 7) * (nwg >> 3) + (bid >> 3);
  const int bx = nid % gridDim.x, by = nid / gridDim.x;
  const int m0 = by * 64, n0 = bx * 128;
  const int w = t >> 6, lane = t & 63, llo = lane & 15, lhi = lane >> 4;
  const int wr = w >> 1, wc = w & 1;

  const int sr = t >> 2, sg = (t & 3) ^ ((t >> 3) & 3);
  const unsigned short* pa = &A[(size_t)(m0 + sr) * K + sg * 8];
  const unsigned short* pb = &Wt[(size_t)(n0 + sr) * K + sg * 8];

#define GSTAGE64(AsX, BsX, koff) do { \
    gl16(pa + (koff), &AsX[t * 8]); \
    gl16(pb + (koff), &BsX[t * 8]); \
    gl16(pb + (size_t)64 * K + (koff), &BsX[2048 + t * 8]); \
  } while (0)

  const int pgo = (lhi ^ ((llo >> 1) & 3)) * 8;

#define GCOMP64(AsX, BsX) do { \
    bf16x8 af[2], bfr[4]; \
    _Pragma("unroll") \
    for (int f = 0; f < 2; f++) \
      af[f] = *reinterpret_cast<const bf16x8*>(&AsX[(wr * 32 + f * 16 + llo) * 32 + pgo]); \
    _Pragma("unroll") \
    for (int f = 0; f < 4; f++) \
      bfr[f] = *reinterpret_cast<const bf16x8*>(&BsX[(wc * 64 + f * 16 + llo) * 32 + pgo]); \
    _Pragma("unroll") \
    for (int fi = 0; fi < 2; fi++) \
      _Pragma("unroll") \
      for (int fj = 0; fj < 4; fj++) \
        acc[fi][fj] = __builtin_amdgcn_mfma_f32_16x16x32_bf16(af[fi], bfr[fj], acc[fi][fj], 0, 0, 0); \
  } while (0)

  f32x4 acc[2][4] = {};
  GSTAGE64(As0, Bs0, 0);
  for (int k0 = 0; k0 < K; k0 += 64) {
    __syncthreads();
    GSTAGE64(As1, Bs1, k0 + 32);
    GCOMP64(As0, Bs0);
    __syncthreads();
    if (k0 + 64 < K) GSTAGE64(As0, Bs0, k0 + 64);
    GCOMP64(As1, Bs1);
  }
#undef GSTAGE64
#undef GCOMP64

  const int row0 = m0 + wr * 32, col0 = n0 + wc * 64;
  #pragma unroll
  for (int fi = 0; fi < 2; fi++)
    #pragma unroll
    for (int fj = 0; fj < 4; fj++)
      #pragma unroll
      for (int i = 0; i < 4; i++) {
        const int row = row0 + fi * 16 + lhi * 4 + i;
        const int col = col0 + fj * 16 + llo;
        float v = acc[fi][fj][i];
        if (HASBIAS) v += bias[col];
        if (HASRES) {
          if (RESBF) v += bf2f(((const unsigned short*)res)[(size_t)row * N + col]);
          else       v += ((const float*)res)[(size_t)row * N + col];
        }
        if (RELU)    v = fmaxf(v, 0.0f);
        if (OUTBF) ((unsigned short*)outp)[(size_t)row * N + col] = f2bf(v);
        else       ((float*)outp)[(size_t)row * N + col] = v;
      }
}

// ---------------------------------------------------------------- attention v5 (round-9 exact)
__global__ __launch_bounds__(256) void attn_k(
    const unsigned short* __restrict__ QKV,   // [8192][1536]
    const unsigned short* __restrict__ VT,    // [bh][64][1024]
    unsigned short* __restrict__ Zb)          // [8192][512]
{
  __shared__ __align__(16) unsigned short Ks0[4096], Vs0[4096];
  __shared__ __align__(16) unsigned short Ks1[4096], Vs1[4096];
  __shared__ __align__(16) unsigned short Ps[8192];   // 4 waves x [32][64]

  const int t = threadIdx.x;
  const int h = blockIdx.x, qt = blockIdx.y, bb = blockIdx.z;
  const int w = t >> 6, lane = t & 63, llo = lane & 15, lhi = lane >> 4;
  const size_t rowb = (size_t)bb * SEQ;
  const int kcol = 512 + h * 64;
  const size_t vtb = (size_t)(bb * 8 + h) * 64 * SEQ;

  // hoist Q fragments; 32 q rows per wave
  bf16x8 aq[2][2];
  #pragma unroll
  for (int mi = 0; mi < 2; mi++)
    #pragma unroll
    for (int ds = 0; ds < 2; ds++)
      aq[mi][ds] = *reinterpret_cast<const bf16x8*>(
          &QKV[(rowb + qt * 128 + w * 32 + mi * 16 + llo) * QKVW + h * 64 + ds * 32 + lhi * 8]);

  // frag-major staging sources (chunk c = iss*256 + t)
  const int cA = t, cB = 256 + t;
  const int gA = cA >> 6, lA = cA & 63, gB = cB >> 6, lB = cB & 63;
  const unsigned short* kpA = &QKV[(rowb + (gA >> 1) * 16 + (lA & 15)) * QKVW + kcol + (gA & 1) * 32 + (lA >> 4) * 8];
  const unsigned short* kpB = &QKV[(rowb + (gB >> 1) * 16 + (lB & 15)) * QKVW + kcol + (gB & 1) * 32 + (lB >> 4) * 8];
  const unsigned short* vpA = &VT[vtb + (size_t)((gA >> 1) * 16 + (lA & 15)) * SEQ + (gA & 1) * 32 + (lA >> 4) * 8];
  const unsigned short* vpB = &VT[vtb + (size_t)((gB >> 1) * 16 + (lB & 15)) * SEQ + (gB & 1) * 32 + (lB >> 4) * 8];

#define ASTAGE(KsX, VsX, ktt) do { \
    gl16(kpA + (size_t)(ktt) * 64 * QKVW, &KsX[cA * 8]); \
    gl16(kpB + (size_t)(ktt) * 64 * QKVW, &KsX[cB * 8]); \
    gl16(vpA + (ktt) * 64, &VsX[cA * 8]); \
    gl16(vpB + (ktt) * 64, &VsX[cB * 8]); \
  } while (0)

  const int psw = w * 2048;      // per-wave [32][64] region (shorts)
  const int lsw = llo & 7;

#define ACOMP(KsX, VsX) do { \
    f32x4 s_[2][4]; \
    _Pragma("unroll") \
    for (int mi = 0; mi < 2; mi++) \
      _Pragma("unroll") \
      for (int fj = 0; fj < 4; fj++) \
        _Pragma("unroll") \
        for (int i = 0; i < 4; i++) s_[mi][fj][i] = -16.0f; \
    _Pragma("unroll") \
    for (int ds = 0; ds < 2; ds++) \
      _Pragma("unroll") \
      for (int fj = 0; fj < 4; fj++) { \
        bf16x8 bk = *reinterpret_cast<const bf16x8*>(&KsX[((fj * 2 + ds) * 64 + lane) * 8]); \
        s_[0][fj] = __builtin_amdgcn_mfma_f32_16x16x32_bf16(bk, aq[0][ds], s_[0][fj], 0, 0, 0); \
        s_[1][fj] = __builtin_amdgcn_mfma_f32_16x16x32_bf16(bk, aq[1][ds], s_[1][fj], 0, 0, 0); \
      } \
    _Pragma("unroll") \
    for (int mi = 0; mi < 2; mi++) \
      _Pragma("unroll") \
      for (int fj = 0; fj < 4; fj++) { \
        const float p0 = exp2_fast(s_[mi][fj][0]); \
        const float p1 = exp2_fast(s_[mi][fj][1]); \
        const float p2 = exp2_fast(s_[mi][fj][2]); \
        const float p3 = exp2_fast(s_[mi][fj][3]); \
        l_[mi] += (p0 + p1) + (p2 + p3); \
        uint2 uv; uv.x = cvtpk_bf16(p0, p1); uv.y = cvtpk_bf16(p2, p3); \
        const int pg = ((fj << 1) | (lhi >> 1)) ^ lsw; \
        *reinterpret_cast<uint2*>(&Ps[psw + (mi * 16 + llo) * 64 + pg * 8 + (lhi & 1) * 4]) = uv; \
      } \
    _Pragma("unroll") \
    for (int ks = 0; ks < 2; ks++) { \
      const int prg = (((ks << 2) | lhi) ^ lsw) << 3; \
      bf16x8 ap0 = *reinterpret_cast<const bf16x8*>(&Ps[psw + llo * 64 + prg]); \
      bf16x8 ap1 = *reinterpret_cast<const bf16x8*>(&Ps[psw + (16 + llo) * 64 + prg]); \
      _Pragma("unroll") \
      for (int fo = 0; fo < 4; fo++) { \
        bf16x8 bv = *reinterpret_cast<const bf16x8*>(&VsX[((fo * 2 + ks) * 64 + lane) * 8]); \
        o_[0][fo] = __builtin_amdgcn_mfma_f32_16x16x32_bf16(ap0, bv, o_[0][fo], 0, 0, 0); \
        o_[1][fo] = __builtin_amdgcn_mfma_f32_16x16x32_bf16(ap1, bv, o_[1][fo], 0, 0, 0); \
      } \
    } \
  } while (0)

  float l_[2] = {0.0f, 0.0f};
  f32x4 o_[2][4] = {};

  ASTAGE(Ks0, Vs0, 0);
  for (int kt = 0; kt < 16; kt += 2) {
    __syncthreads();
    ASTAGE(Ks1, Vs1, kt + 1);
    ACOMP(Ks0, Vs0);
    __syncthreads();
    if (kt + 2 < 16) ASTAGE(Ks0, Vs0, kt + 2);
    ACOMP(Ks1, Vs1);
  }
#undef ASTAGE
#undef ACOMP

  // l_[mi] holds partial denom for q=llo (group mi); reduce across lhi lanes
  #pragma unroll
  for (int mi = 0; mi < 2; mi++) {
    l_[mi] += __shfl_xor(l_[mi], 16);
    l_[mi] += __shfl_xor(l_[mi], 32);
    l_[mi] = 1.0f / l_[mi];
  }

  #pragma unroll
  for (int mi = 0; mi < 2; mi++)
    #pragma unroll
    for (int i = 0; i < 4; i++) {
      const float li = __shfl(l_[mi], lhi * 4 + i);   // linv for q=lhi*4+i
      #pragma unroll
      for (int fo = 0; fo < 4; fo++) {
        const float v = o_[mi][fo][i] * li;
        Zb[(rowb + qt * 128 + w * 32 + mi * 16 + lhi * 4 + i) * 512 + h * 64 + fo * 16 + llo] = f2bf(v);
      }
    }
}

// ---------------------------------------------------------------- driver
extern "C" void kernel_launch(void* const* d_in, const int* in_sizes, int n_in,
                              void* d_out, int out_size, void* d_ws, size_t ws_size,
                              hipStream_t stream)
{
  const float* x   = (const float*)d_in[0];
  const float* Wq  = (const float*)d_in[1];
  const float* Wk  = (const float*)d_in[2];
  const float* Wv  = (const float*)d_in[3];
  const float* Wo  = (const float*)d_in[4];
  const float* W1  = (const float*)d_in[5];
  const float* b1  = (const float*)d_in[6];
  const float* W2  = (const float*)d_in[7];
  const float* b2  = (const float*)d_in[8];
  const float* ga  = (const float*)d_in[9];
  const float* ba  = (const float*)d_in[10];
  const float* gf  = (const float*)d_in[11];
  const float* bfn = (const float*)d_in[12];
  float* out = (float*)d_out;

  char* p = (char*)d_ws;
  auto alloc = [&](size_t bytes) { void* r = (void*)p; p += (bytes + 255) & ~(size_t)255; return r; };
  unsigned short* E0 = (unsigned short*)alloc((size_t)ROWS * 512 * 2);   // bf16 residual
  unsigned short* E1 = (unsigned short*)alloc((size_t)ROWS * 512 * 2);   // bf16 residual
  unsigned short* Zbf   = (unsigned short*)alloc((size_t)ROWS * 512 * 2);
  unsigned short* QKVbf = (unsigned short*)alloc((size_t)ROWS * QKVW * 2);
  unsigned short* H1bf  = (unsigned short*)alloc((size_t)ROWS * 2048 * 2);
  unsigned short* VT    = H1bf;   // aliases front 8MB of H1bf (disjoint in time)
  unsigned short* WtQKV = (unsigned short*)alloc(6ull * QKVW * 512 * 2);
  unsigned short* WtO   = (unsigned short*)alloc(6ull * 512 * 512 * 2);
  unsigned short* Wt1   = (unsigned short*)alloc(6ull * 2048 * 512 * 2);
  unsigned short* Wt2   = (unsigned short*)alloc(6ull * 512 * 2048 * 2);
  float2* MUI0 = (float2*)alloc((size_t)ROWS * 8);
  float2* MUI1 = (float2*)alloc((size_t)ROWS * 8);
  float* C1qkv = (float*)alloc(6ull * QKVW * 4);
  float* C2qkv = (float*)alloc(6ull * QKVW * 4);
  float* C1f   = (float*)alloc(6ull * 2048 * 4);
  float* C2f   = (float*)alloc(6ull * 2048 * 4);

  // weight prep: g folded into Wq/Wk/Wv/W1; Wq also carries 0.125*log2e.
  const float qscale = 0.125f * 1.44269504f;
  wprep4_k<<<dim3(16, 16, 24), 256, 0, stream>>>(Wq, Wk, Wv, Wo, ga, WtQKV, WtO, qscale);
  wprep1_k<<<dim3(64, 16, 6), 256, 0, stream>>>(W1, gf, Wt1);
  transpose_cast_k<<<dim3(16, 64, 6), 256, 0, stream>>>(W2, Wt2, 2048, 512, 1048576, 1.0f);
  // LN-fold constant vectors
  cvec_k<<<dim3(8, 6), 256, 0, stream>>>(Wq, ga, ba, nullptr, qscale, C1qkv,        C2qkv,        512, QKVW);
  cvec_k<<<dim3(8, 6), 256, 0, stream>>>(Wk, ga, ba, nullptr, 1.0f,   C1qkv + 512,  C2qkv + 512,  512, QKVW);
  cvec_k<<<dim3(8, 6), 256, 0, stream>>>(Wv, ga, ba, nullptr, 1.0f,   C1qkv + 1024, C2qkv + 1024, 512, QKVW);
  cvec_k<<<dim3(32, 6), 256, 0, stream>>>(W1, gf, bfn, b1,    1.0f,   C1f,          C2f,          2048, 2048);
  // x -> bf16 residual seed
  cvt_k<<<2048, 256, 0, stream>>>(x, E0, ROWS * 512 / 8);

  for (int l = 0; l < 6; l++) {
    // attention LN folded into QKV GEMM (reads raw E0 + row stats)
    stat_k<<<2048, 256, 0, stream>>>(E0, MUI0, ROWS);
    gemm128_k<false, false, false, true, true, true><<<dim3(12, 64), 256, 0, stream>>>(
        E0, WtQKV + (size_t)l * QKVW * 512, nullptr, nullptr,
        MUI0, C1qkv + (size_t)l * QKVW, C2qkv + (size_t)l * QKVW,
        QKVbf, VT, ROWS, QKVW, 512);
    attn_k<<<dim3(8, 8, 8), 256, 0, stream>>>(QKVbf, VT, Zbf);
    gemm64_k<false, false, true, true, true><<<dim3(4, 128), 256, 0, stream>>>(
        Zbf, WtO + (size_t)l * 262144, nullptr, E0, E1, ROWS, 512, 512);
    // FFN LN folded into W1 GEMM (reads raw E1 + row stats); bias in C2f
    stat_k<<<2048, 256, 0, stream>>>(E1, MUI1, ROWS);
    gemm128_k<true, false, false, true, false, true><<<dim3(16, 64), 256, 0, stream>>>(
        E1, Wt1 + (size_t)l * 1048576, nullptr, nullptr,
        MUI1, C1f + (size_t)l * 2048, C2f + (size_t)l * 2048,
        H1bf, nullptr, ROWS, 2048, 512);
    if (l < 5)
      gemm64_k<false, true, true, true, true><<<dim3(4, 128), 256, 0, stream>>>(
          H1bf, Wt2 + (size_t)l * 1048576, b2 + l * 512, E1, E0, ROWS, 512, 2048);
    else
      gemm64_k<false, true, true, false, true><<<dim3(4, 128), 256, 0, stream>>>(
          H1bf, Wt2 + (size_t)l * 1048576, b2 + l * 512, E1, out, ROWS, 512, 2048);
  }
}

// Round 16
// 787.966 us; speedup vs baseline: 1.1801x; 1.1801x over previous
//
#include <hip/hip_runtime.h>

// 6-layer pre-LN encoder, B=8 S=1024 D=512 H=8 DH=64 FFN=2048.
// Round 16: REVERT to round-13 exactly (best: 797.5us) — the LN-fold (R15),
// split-K (R11), counted-vmcnt (R10), and tile changes (R7/R14) all
// regressed. Only R14's merged QKVO weight-prep dispatch is kept (neutral
// to slightly positive, -3 dispatches).

#define SEQ 1024
#define ROWS 8192
#define QKVW 1536

using bf16x8 = __attribute__((ext_vector_type(8))) short;
using f32x4  = __attribute__((ext_vector_type(4))) float;

__device__ __forceinline__ unsigned short f2bf(float f) {
  union { float f; unsigned u; } v; v.f = f;
  unsigned r = v.u + 0x7FFFu + ((v.u >> 16) & 1u);   // RNE
  return (unsigned short)(r >> 16);
}
__device__ __forceinline__ float bf2f(unsigned short b) {
  union { unsigned u; float f; } v; v.u = ((unsigned)b) << 16;
  return v.f;
}

__device__ __forceinline__ float exp2_fast(float x) {
  float r;
  asm("v_exp_f32 %0, %1" : "=v"(r) : "v"(x));
  return r;
}

__device__ __forceinline__ unsigned cvtpk_bf16(float a, float b) {
  unsigned r;   // low16 = bf16(a), high16 = bf16(b)
  asm("v_cvt_pk_bf16_f32 %0, %1, %2" : "=v"(r) : "v"(a), "v"(b));
  return r;
}

__device__ __forceinline__ void gl16(const void* g, void* l) {
  typedef const unsigned int __attribute__((address_space(1)))* GP;
  typedef unsigned int __attribute__((address_space(3)))* LP;
  __builtin_amdgcn_global_load_lds((GP)g, (LP)l, 16, 0, 0);
}

// ---------------------------------------------------------------- weight prep
__global__ __launch_bounds__(256) void transpose_cast_k(
    const float* __restrict__ W, unsigned short* __restrict__ Wt,
    int K, int N, int lstride, float scale)
{
  __shared__ float tile[32][33];
  const int l = blockIdx.z;
  const float* Wl = W + (size_t)l * K * N;
  unsigned short* Wtl = Wt + (size_t)l * lstride;
  const int k0 = blockIdx.y * 32, n0 = blockIdx.x * 32;
  const int tx = threadIdx.x & 31, ty = threadIdx.x >> 5;
  #pragma unroll
  for (int i = ty; i < 32; i += 8)
    tile[i][tx] = Wl[(size_t)(k0 + i) * N + n0 + tx];
  __syncthreads();
  #pragma unroll
  for (int i = ty; i < 32; i += 8)
    Wtl[(size_t)(n0 + i) * K + k0 + tx] = f2bf(tile[tx][i] * scale);
}

// QKVO combined prep: z = l*4 + {0:Q,1:K,2:V,3:O}; all 512x512.
__global__ __launch_bounds__(256) void wprep4_k(
    const float* __restrict__ Wq, const float* __restrict__ Wk,
    const float* __restrict__ Wv, const float* __restrict__ Wo,
    unsigned short* __restrict__ WtQKV, unsigned short* __restrict__ WtO,
    float qscale)
{
  __shared__ float tile[32][33];
  const int z = blockIdx.z, l = z >> 2, which = z & 3;
  const float* W;
  unsigned short* Wtl;
  float scale = 1.0f;
  switch (which) {
    case 0: W = Wq; Wtl = WtQKV + (size_t)l * QKVW * 512;          scale = qscale; break;
    case 1: W = Wk; Wtl = WtQKV + (size_t)l * QKVW * 512 + 262144; break;
    case 2: W = Wv; Wtl = WtQKV + (size_t)l * QKVW * 512 + 524288; break;
    default: W = Wo; Wtl = WtO + (size_t)l * 262144;               break;
  }
  const float* Wl = W + (size_t)l * 512 * 512;
  const int k0 = blockIdx.y * 32, n0 = blockIdx.x * 32;
  const int tx = threadIdx.x & 31, ty = threadIdx.x >> 5;
  #pragma unroll
  for (int i = ty; i < 32; i += 8)
    tile[i][tx] = Wl[(size_t)(k0 + i) * 512 + n0 + tx];
  __syncthreads();
  #pragma unroll
  for (int i = ty; i < 32; i += 8)
    Wtl[(size_t)(n0 + i) * 512 + k0 + tx] = f2bf(tile[tx][i] * scale);
}

// ---------------------------------------------------------------- f32 -> bf16 convert (x, once)
__global__ __launch_bounds__(256) void cvt_k(
    const float* __restrict__ x, unsigned short* __restrict__ y, int n8)
{
  const int i = blockIdx.x * 256 + threadIdx.x;
  if (i >= n8) return;
  const float4 a = reinterpret_cast<const float4*>(x)[i * 2];
  const float4 b = reinterpret_cast<const float4*>(x)[i * 2 + 1];
  uint4 o;
  o.x = (unsigned)f2bf(a.x) | ((unsigned)f2bf(a.y) << 16);
  o.y = (unsigned)f2bf(a.z) | ((unsigned)f2bf(a.w) << 16);
  o.z = (unsigned)f2bf(b.x) | ((unsigned)f2bf(b.y) << 16);
  o.w = (unsigned)f2bf(b.z) | ((unsigned)f2bf(b.w) << 16);
  reinterpret_cast<uint4*>(y)[i] = o;
}

// ---------------------------------------------------------------- layernorm (bf16 in, bf16 out)
__global__ __launch_bounds__(256) void ln_k(
    const unsigned short* __restrict__ x, const float* __restrict__ g,
    const float* __restrict__ be, unsigned short* __restrict__ y, int rows)
{
  const int wid = (blockIdx.x << 2) | (threadIdx.x >> 6);
  const int lane = threadIdx.x & 63;
  if (wid >= rows) return;
  const uint4 u = reinterpret_cast<const uint4*>(x + (size_t)wid * 512)[lane];
  float f[8];
  f[0] = bf2f((unsigned short)(u.x & 0xffffu)); f[1] = bf2f((unsigned short)(u.x >> 16));
  f[2] = bf2f((unsigned short)(u.y & 0xffffu)); f[3] = bf2f((unsigned short)(u.y >> 16));
  f[4] = bf2f((unsigned short)(u.z & 0xffffu)); f[5] = bf2f((unsigned short)(u.z >> 16));
  f[6] = bf2f((unsigned short)(u.w & 0xffffu)); f[7] = bf2f((unsigned short)(u.w >> 16));
  float s = (f[0] + f[1] + f[2] + f[3]) + (f[4] + f[5] + f[6] + f[7]);
  #pragma unroll
  for (int m = 32; m >= 1; m >>= 1) s += __shfl_xor(s, m);
  const float mu = s * (1.0f / 512.0f);
  float d[8], q = 0.0f;
  #pragma unroll
  for (int j = 0; j < 8; j++) { d[j] = f[j] - mu; q += d[j] * d[j]; }
  #pragma unroll
  for (int m = 32; m >= 1; m >>= 1) q += __shfl_xor(q, m);
  const float inv = rsqrtf(q * (1.0f / 512.0f) + 1e-3f);
  const float4 g0 = reinterpret_cast<const float4*>(g)[lane * 2];
  const float4 g1 = reinterpret_cast<const float4*>(g)[lane * 2 + 1];
  const float4 h0 = reinterpret_cast<const float4*>(be)[lane * 2];
  const float4 h1 = reinterpret_cast<const float4*>(be)[lane * 2 + 1];
  uint4 o;
  o.x = (unsigned)f2bf(d[0] * inv * g0.x + h0.x) | ((unsigned)f2bf(d[1] * inv * g0.y + h0.y) << 16);
  o.y = (unsigned)f2bf(d[2] * inv * g0.z + h0.z) | ((unsigned)f2bf(d[3] * inv * g0.w + h0.w) << 16);
  o.z = (unsigned)f2bf(d[4] * inv * g1.x + h1.x) | ((unsigned)f2bf(d[5] * inv * g1.y + h1.y) << 16);
  o.w = (unsigned)f2bf(d[6] * inv * g1.z + h1.z) | ((unsigned)f2bf(d[7] * inv * g1.w + h1.w) << 16);
  reinterpret_cast<uint4*>(y + (size_t)wid * 512)[lane] = o;
}

// ---------------------------------------------------------------- GEMM 128x128, BK=32, dbuf 2-phase
// QKV=true: blocks with n0>=1024 (the V third) write transposed into vt.
template<bool RELU, bool HASBIAS, bool HASRES, bool OUTBF, bool QKV>
__global__ __launch_bounds__(256) void gemm128_k(
    const unsigned short* __restrict__ A,
    const unsigned short* __restrict__ Wt,
    const float* __restrict__ bias,
    const float* __restrict__ res,
    void* __restrict__ outp, unsigned short* __restrict__ vt,
    int M, int N, int K)
{
  __shared__ __align__(16) unsigned short As0[4096], Bs0[4096];
  __shared__ __align__(16) unsigned short As1[4096], Bs1[4096];
  const int t = threadIdx.x;
  const int nwg = gridDim.x * gridDim.y;
  const int bid = blockIdx.y * gridDim.x + blockIdx.x;
  const int nid = (bid & 7) * (nwg >> 3) + (bid >> 3);
  const int bx = nid % gridDim.x, by = nid / gridDim.x;
  const int m0 = by * 128, n0 = bx * 128;
  const int w = t >> 6, lane = t & 63, llo = lane & 15, lhi = lane >> 4;
  const int wr = w >> 1, wc = w & 1;

  const int sr = t >> 2, sg = (t & 3) ^ ((t >> 3) & 3);
  const unsigned short* pa = &A[(size_t)(m0 + sr) * K + sg * 8];
  const unsigned short* pb = &Wt[(size_t)(n0 + sr) * K + sg * 8];

#define GSTAGE128(AsX, BsX, koff) do { \
    gl16(pa + (koff), &AsX[t * 8]); \
    gl16(pa + (size_t)64 * K + (koff), &AsX[2048 + t * 8]); \
    gl16(pb + (koff), &BsX[t * 8]); \
    gl16(pb + (size_t)64 * K + (koff), &BsX[2048 + t * 8]); \
  } while (0)

  const int pgo = (lhi ^ ((llo >> 1) & 3)) * 8;

#define GCOMP128(AsX, BsX) do { \
    bf16x8 af[4], bfr[4]; \
    _Pragma("unroll") \
    for (int f = 0; f < 4; f++) { \
      af[f]  = *reinterpret_cast<const bf16x8*>(&AsX[(wr * 64 + f * 16 + llo) * 32 + pgo]); \
      bfr[f] = *reinterpret_cast<const bf16x8*>(&BsX[(wc * 64 + f * 16 + llo) * 32 + pgo]); \
    } \
    _Pragma("unroll") \
    for (int fi = 0; fi < 4; fi++) \
      _Pragma("unroll") \
      for (int fj = 0; fj < 4; fj++) \
        acc[fi][fj] = __builtin_amdgcn_mfma_f32_16x16x32_bf16(af[fi], bfr[fj], acc[fi][fj], 0, 0, 0); \
  } while (0)

  f32x4 acc[4][4] = {};
  GSTAGE128(As0, Bs0, 0);
  for (int k0 = 0; k0 < K; k0 += 64) {
    __syncthreads();
    GSTAGE128(As1, Bs1, k0 + 32);
    GCOMP128(As0, Bs0);
    __syncthreads();
    if (k0 + 64 < K) GSTAGE128(As0, Bs0, k0 + 64);
    GCOMP128(As1, Bs1);
  }
#undef GSTAGE128
#undef GCOMP128

  if (QKV && n0 >= 1024) {
    // V-section: write transposed directly into VT[bh][dv][s].
    const int bb2 = by >> 3;              // batch (m0/1024)
    const int s0 = (by & 7) * 128;        // s base within batch
    const int bh = bb2 * 8 + ((bx - 8) << 1) + wc;
    #pragma unroll
    for (int fi = 0; fi < 4; fi++)
      #pragma unroll
      for (int fj = 0; fj < 4; fj++) {
        ushort4 o;
        o.x = f2bf(acc[fi][fj][0]);
        o.y = f2bf(acc[fi][fj][1]);
        o.z = f2bf(acc[fi][fj][2]);
        o.w = f2bf(acc[fi][fj][3]);
        const int dv = fj * 16 + llo;
        *reinterpret_cast<ushort4*>(
            &vt[((size_t)bh * 64 + dv) * SEQ + s0 + wr * 64 + fi * 16 + lhi * 4]) = o;
      }
    return;
  }

  const int row0 = m0 + wr * 64, col0 = n0 + wc * 64;
  #pragma unroll
  for (int fi = 0; fi < 4; fi++)
    #pragma unroll
    for (int fj = 0; fj < 4; fj++)
      #pragma unroll
      for (int i = 0; i < 4; i++) {
        const int row = row0 + fi * 16 + lhi * 4 + i;
        const int col = col0 + fj * 16 + llo;
        float v = acc[fi][fj][i];
        if (HASBIAS) v += bias[col];
        if (HASRES)  v += res[(size_t)row * N + col];
        if (RELU)    v = fmaxf(v, 0.0f);
        if (OUTBF) ((unsigned short*)outp)[(size_t)row * N + col] = f2bf(v);
        else       ((float*)outp)[(size_t)row * N + col] = v;
      }
}

// ---------------------------------------------------------------- GEMM 64x128, BK=32, dbuf 2-phase
// RESBF: residual tensor is bf16.
template<bool RELU, bool HASBIAS, bool HASRES, bool OUTBF, bool RESBF>
__global__ __launch_bounds__(256) void gemm64_k(
    const unsigned short* __restrict__ A,
    const unsigned short* __restrict__ Wt,
    const float* __restrict__ bias,
    const void* __restrict__ res,
    void* __restrict__ outp, int M, int N, int K)
{
  __shared__ __align__(16) unsigned short As0[2048], Bs0[4096];
  __shared__ __align__(16) unsigned short As1[2048], Bs1[4096];
  const int t = threadIdx.x;
  const int nwg = gridDim.x * gridDim.y;
  const int bid = blockIdx.y * gridDim.x + blockIdx.x;
  const int nid = (bid & 7) * (nwg >> 3) + (bid >> 3);
  const int bx = nid % gridDim.x, by = nid / gridDim.x;
  const int m0 = by * 64, n0 = bx * 128;
  const int w = t >> 6, lane = t & 63, llo = lane & 15, lhi = lane >> 4;
  const int wr = w >> 1, wc = w & 1;

  const int sr = t >> 2, sg = (t & 3) ^ ((t >> 3) & 3);
  const unsigned short* pa = &A[(size_t)(m0 + sr) * K + sg * 8];
  const unsigned short* pb = &Wt[(size_t)(n0 + sr) * K + sg * 8];

#define GSTAGE64(AsX, BsX, koff) do { \
    gl16(pa + (koff), &AsX[t * 8]); \
    gl16(pb + (koff), &BsX[t * 8]); \
    gl16(pb + (size_t)64 * K + (koff), &BsX[2048 + t * 8]); \
  } while (0)

  const int pgo = (lhi ^ ((llo >> 1) & 3)) * 8;

#define GCOMP64(AsX, BsX) do { \
    bf16x8 af[2], bfr[4]; \
    _Pragma("unroll") \
    for (int f = 0; f < 2; f++) \
      af[f] = *reinterpret_cast<const bf16x8*>(&AsX[(wr * 32 + f * 16 + llo) * 32 + pgo]); \
    _Pragma("unroll") \
    for (int f = 0; f < 4; f++) \
      bfr[f] = *reinterpret_cast<const bf16x8*>(&BsX[(wc * 64 + f * 16 + llo) * 32 + pgo]); \
    _Pragma("unroll") \
    for (int fi = 0; fi < 2; fi++) \
      _Pragma("unroll") \
      for (int fj = 0; fj < 4; fj++) \
        acc[fi][fj] = __builtin_amdgcn_mfma_f32_16x16x32_bf16(af[fi], bfr[fj], acc[fi][fj], 0, 0, 0); \
  } while (0)

  f32x4 acc[2][4] = {};
  GSTAGE64(As0, Bs0, 0);
  for (int k0 = 0; k0 < K; k0 += 64) {
    __syncthreads();
    GSTAGE64(As1, Bs1, k0 + 32);
    GCOMP64(As0, Bs0);
    __syncthreads();
    if (k0 + 64 < K) GSTAGE64(As0, Bs0, k0 + 64);
    GCOMP64(As1, Bs1);
  }
#undef GSTAGE64
#undef GCOMP64

  const int row0 = m0 + wr * 32, col0 = n0 + wc * 64;
  #pragma unroll
  for (int fi = 0; fi < 2; fi++)
    #pragma unroll
    for (int fj = 0; fj < 4; fj++)
      #pragma unroll
      for (int i = 0; i < 4; i++) {
        const int row = row0 + fi * 16 + lhi * 4 + i;
        const int col = col0 + fj * 16 + llo;
        float v = acc[fi][fj][i];
        if (HASBIAS) v += bias[col];
        if (HASRES) {
          if (RESBF) v += bf2f(((const unsigned short*)res)[(size_t)row * N + col]);
          else       v += ((const float*)res)[(size_t)row * N + col];
        }
        if (RELU)    v = fmaxf(v, 0.0f);
        if (OUTBF) ((unsigned short*)outp)[(size_t)row * N + col] = f2bf(v);
        else       ((float*)outp)[(size_t)row * N + col] = v;
      }
}

// ---------------------------------------------------------------- attention v5 (round-9 exact)
__global__ __launch_bounds__(256) void attn_k(
    const unsigned short* __restrict__ QKV,   // [8192][1536]
    const unsigned short* __restrict__ VT,    // [bh][64][1024]
    unsigned short* __restrict__ Zb)          // [8192][512]
{
  __shared__ __align__(16) unsigned short Ks0[4096], Vs0[4096];
  __shared__ __align__(16) unsigned short Ks1[4096], Vs1[4096];
  __shared__ __align__(16) unsigned short Ps[8192];   // 4 waves x [32][64]

  const int t = threadIdx.x;
  const int h = blockIdx.x, qt = blockIdx.y, bb = blockIdx.z;
  const int w = t >> 6, lane = t & 63, llo = lane & 15, lhi = lane >> 4;
  const size_t rowb = (size_t)bb * SEQ;
  const int kcol = 512 + h * 64;
  const size_t vtb = (size_t)(bb * 8 + h) * 64 * SEQ;

  // hoist Q fragments (0.125*log2e folded into Wq); 32 q rows per wave
  bf16x8 aq[2][2];
  #pragma unroll
  for (int mi = 0; mi < 2; mi++)
    #pragma unroll
    for (int ds = 0; ds < 2; ds++)
      aq[mi][ds] = *reinterpret_cast<const bf16x8*>(
          &QKV[(rowb + qt * 128 + w * 32 + mi * 16 + llo) * QKVW + h * 64 + ds * 32 + lhi * 8]);

  // frag-major staging sources (chunk c = iss*256 + t)
  const int cA = t, cB = 256 + t;
  const int gA = cA >> 6, lA = cA & 63, gB = cB >> 6, lB = cB & 63;
  const unsigned short* kpA = &QKV[(rowb + (gA >> 1) * 16 + (lA & 15)) * QKVW + kcol + (gA & 1) * 32 + (lA >> 4) * 8];
  const unsigned short* kpB = &QKV[(rowb + (gB >> 1) * 16 + (lB & 15)) * QKVW + kcol + (gB & 1) * 32 + (lB >> 4) * 8];
  const unsigned short* vpA = &VT[vtb + (size_t)((gA >> 1) * 16 + (lA & 15)) * SEQ + (gA & 1) * 32 + (lA >> 4) * 8];
  const unsigned short* vpB = &VT[vtb + (size_t)((gB >> 1) * 16 + (lB & 15)) * SEQ + (gB & 1) * 32 + (lB >> 4) * 8];

#define ASTAGE(KsX, VsX, ktt) do { \
    gl16(kpA + (size_t)(ktt) * 64 * QKVW, &KsX[cA * 8]); \
    gl16(kpB + (size_t)(ktt) * 64 * QKVW, &KsX[cB * 8]); \
    gl16(vpA + (ktt) * 64, &VsX[cA * 8]); \
    gl16(vpB + (ktt) * 64, &VsX[cB * 8]); \
  } while (0)

  const int psw = w * 2048;      // per-wave [32][64] region (shorts)
  const int lsw = llo & 7;

#define ACOMP(KsX, VsX) do { \
    f32x4 s_[2][4]; \
    _Pragma("unroll") \
    for (int mi = 0; mi < 2; mi++) \
      _Pragma("unroll") \
      for (int fj = 0; fj < 4; fj++) \
        _Pragma("unroll") \
        for (int i = 0; i < 4; i++) s_[mi][fj][i] = -16.0f; \
    _Pragma("unroll") \
    for (int ds = 0; ds < 2; ds++) \
      _Pragma("unroll") \
      for (int fj = 0; fj < 4; fj++) { \
        bf16x8 bk = *reinterpret_cast<const bf16x8*>(&KsX[((fj * 2 + ds) * 64 + lane) * 8]); \
        s_[0][fj] = __builtin_amdgcn_mfma_f32_16x16x32_bf16(bk, aq[0][ds], s_[0][fj], 0, 0, 0); \
        s_[1][fj] = __builtin_amdgcn_mfma_f32_16x16x32_bf16(bk, aq[1][ds], s_[1][fj], 0, 0, 0); \
      } \
    _Pragma("unroll") \
    for (int mi = 0; mi < 2; mi++) \
      _Pragma("unroll") \
      for (int fj = 0; fj < 4; fj++) { \
        const float p0 = exp2_fast(s_[mi][fj][0]); \
        const float p1 = exp2_fast(s_[mi][fj][1]); \
        const float p2 = exp2_fast(s_[mi][fj][2]); \
        const float p3 = exp2_fast(s_[mi][fj][3]); \
        l_[mi] += (p0 + p1) + (p2 + p3); \
        uint2 uv; uv.x = cvtpk_bf16(p0, p1); uv.y = cvtpk_bf16(p2, p3); \
        const int pg = ((fj << 1) | (lhi >> 1)) ^ lsw; \
        *reinterpret_cast<uint2*>(&Ps[psw + (mi * 16 + llo) * 64 + pg * 8 + (lhi & 1) * 4]) = uv; \
      } \
    _Pragma("unroll") \
    for (int ks = 0; ks < 2; ks++) { \
      const int prg = (((ks << 2) | lhi) ^ lsw) << 3; \
      bf16x8 ap0 = *reinterpret_cast<const bf16x8*>(&Ps[psw + llo * 64 + prg]); \
      bf16x8 ap1 = *reinterpret_cast<const bf16x8*>(&Ps[psw + (16 + llo) * 64 + prg]); \
      _Pragma("unroll") \
      for (int fo = 0; fo < 4; fo++) { \
        bf16x8 bv = *reinterpret_cast<const bf16x8*>(&VsX[((fo * 2 + ks) * 64 + lane) * 8]); \
        o_[0][fo] = __builtin_amdgcn_mfma_f32_16x16x32_bf16(ap0, bv, o_[0][fo], 0, 0, 0); \
        o_[1][fo] = __builtin_amdgcn_mfma_f32_16x16x32_bf16(ap1, bv, o_[1][fo], 0, 0, 0); \
      } \
    } \
  } while (0)

  float l_[2] = {0.0f, 0.0f};
  f32x4 o_[2][4] = {};

  ASTAGE(Ks0, Vs0, 0);
  for (int kt = 0; kt < 16; kt += 2) {
    __syncthreads();
    ASTAGE(Ks1, Vs1, kt + 1);
    ACOMP(Ks0, Vs0);
    __syncthreads();
    if (kt + 2 < 16) ASTAGE(Ks0, Vs0, kt + 2);
    ACOMP(Ks1, Vs1);
  }
#undef ASTAGE
#undef ACOMP

  // l_[mi] holds partial denom for q=llo (group mi); reduce across lhi lanes
  #pragma unroll
  for (int mi = 0; mi < 2; mi++) {
    l_[mi] += __shfl_xor(l_[mi], 16);
    l_[mi] += __shfl_xor(l_[mi], 32);
    l_[mi] = 1.0f / l_[mi];
  }

  #pragma unroll
  for (int mi = 0; mi < 2; mi++)
    #pragma unroll
    for (int i = 0; i < 4; i++) {
      const float li = __shfl(l_[mi], lhi * 4 + i);   // linv for q=lhi*4+i
      #pragma unroll
      for (int fo = 0; fo < 4; fo++) {
        const float v = o_[mi][fo][i] * li;
        Zb[(rowb + qt * 128 + w * 32 + mi * 16 + lhi * 4 + i) * 512 + h * 64 + fo * 16 + llo] = f2bf(v);
      }
    }
}

// ---------------------------------------------------------------- driver
extern "C" void kernel_launch(void* const* d_in, const int* in_sizes, int n_in,
                              void* d_out, int out_size, void* d_ws, size_t ws_size,
                              hipStream_t stream)
{
  const float* x   = (const float*)d_in[0];
  const float* Wq  = (const float*)d_in[1];
  const float* Wk  = (const float*)d_in[2];
  const float* Wv  = (const float*)d_in[3];
  const float* Wo  = (const float*)d_in[4];
  const float* W1  = (const float*)d_in[5];
  const float* b1  = (const float*)d_in[6];
  const float* W2  = (const float*)d_in[7];
  const float* b2  = (const float*)d_in[8];
  const float* ga  = (const float*)d_in[9];
  const float* ba  = (const float*)d_in[10];
  const float* gf  = (const float*)d_in[11];
  const float* bfn = (const float*)d_in[12];
  float* out = (float*)d_out;

  char* p = (char*)d_ws;
  auto alloc = [&](size_t bytes) { void* r = (void*)p; p += (bytes + 255) & ~(size_t)255; return r; };
  unsigned short* E0 = (unsigned short*)alloc((size_t)ROWS * 512 * 2);   // bf16 residual
  unsigned short* E1 = (unsigned short*)alloc((size_t)ROWS * 512 * 2);   // bf16 residual
  unsigned short* Ybf   = (unsigned short*)alloc((size_t)ROWS * 512 * 2);
  unsigned short* QKVbf = (unsigned short*)alloc((size_t)ROWS * QKVW * 2);
  unsigned short* H1bf  = (unsigned short*)alloc((size_t)ROWS * 2048 * 2);
  unsigned short* VT    = H1bf;   // aliases front 8MB of H1bf (disjoint in time)
  unsigned short* WtQKV = (unsigned short*)alloc(6ull * QKVW * 512 * 2);
  unsigned short* WtO   = (unsigned short*)alloc(6ull * 512 * 512 * 2);
  unsigned short* Wt1   = (unsigned short*)alloc(6ull * 2048 * 512 * 2);
  unsigned short* Wt2   = (unsigned short*)alloc(6ull * 512 * 2048 * 2);
  unsigned short* Zbf   = Ybf;

  // weight prep (Wq carries softmax scale AND log2e for exp2-domain softmax)
  const float qscale = 0.125f * 1.44269504f;
  wprep4_k<<<dim3(16, 16, 24), 256, 0, stream>>>(Wq, Wk, Wv, Wo, WtQKV, WtO, qscale);
  transpose_cast_k<<<dim3(64, 16, 6), 256, 0, stream>>>(W1, Wt1, 512, 2048, 1048576, 1.0f);
  transpose_cast_k<<<dim3(16, 64, 6), 256, 0, stream>>>(W2, Wt2, 2048, 512, 1048576, 1.0f);
  // x -> bf16 residual seed
  cvt_k<<<2048, 256, 0, stream>>>(x, E0, ROWS * 512 / 8);

  for (int l = 0; l < 6; l++) {
    // pre-LN attention (QKV GEMM writes Q,K to QKVbf and V transposed to VT)
    ln_k<<<2048, 256, 0, stream>>>(E0, ga + l * 512, ba + l * 512, Ybf, ROWS);
    gemm128_k<false, false, false, true, true><<<dim3(12, 64), 256, 0, stream>>>(
        Ybf, WtQKV + (size_t)l * QKVW * 512, nullptr, nullptr, QKVbf, VT, ROWS, QKVW, 512);
    attn_k<<<dim3(8, 8, 8), 256, 0, stream>>>(QKVbf, VT, Zbf);
    gemm64_k<false, false, true, true, true><<<dim3(4, 128), 256, 0, stream>>>(
        Zbf, WtO + (size_t)l * 262144, nullptr, E0, E1, ROWS, 512, 512);
    // pre-LN FFN
    ln_k<<<2048, 256, 0, stream>>>(E1, gf + l * 512, bfn + l * 512, Ybf, ROWS);
    gemm128_k<true, true, false, true, false><<<dim3(16, 64), 256, 0, stream>>>(
        Ybf, Wt1 + (size_t)l * 1048576, b1 + l * 2048, nullptr, H1bf, nullptr, ROWS, 2048, 512);
    if (l < 5)
      gemm64_k<false, true, true, true, true><<<dim3(4, 128), 256, 0, stream>>>(
          H1bf, Wt2 + (size_t)l * 1048576, b2 + l * 512, E1, E0, ROWS, 512, 2048);
    else
      gemm64_k<false, true, true, false, true><<<dim3(4, 128), 256, 0, stream>>>(
          H1bf, Wt2 + (size_t)l * 1048576, b2 + l * 512, E1, out, ROWS, 512, 2048);
  }
}